// Round 7
// baseline (254.433 us; speedup 1.0000x reference)
//
#include <hip/hip_runtime.h>
#include <hip/hip_bf16.h>

// Problem constants (fixed by setup_inputs):
//   bs=8, nq=1500, C=2  -> NI = 12000 rows
//   total_tgt = 4800    -> NJ = 4800 cols
// Output: [NI][NJ] f32 = 230.4 MB  -> write-BW bound (~37 us @6.3 TB/s).
// In-window harness poison-fill (921.6 MB, ~140 us) sets the total floor ~180 us.
//
// C[i,j] = softplus(x0)+softplus(x1) - t0*x0 - t1*x1 + 5*(|px-tx|+|py-ty|)
// (log_sigmoid(x) - log_sigmoid(-x) = x; mean-over-2 /2 cancels COST_CLASS=2)
//
// R7: cmat restructured as a 1D grid-stride linear writer (fill-shaped) to
// A/B against the 2D tiled writers of R1/R6 which were structure-identical
// at 229 us total.

#define NI 12000
#define NJ 4800
#define NJF (NJ / 4)          // 1200 float4 per row
#define NTOT (NI * NJF)       // 14,400,000 float4 outputs

typedef float f32x4 __attribute__((ext_vector_type(4)));

// ---- precompute: per-row quad (base,-x0,-x1,px) + py, per-target (t0,t1,tx,ty)
__global__ __launch_bounds__(256) void precompute_kernel(
    const float* __restrict__ pred_logits,   // [NI][2]
    const float* __restrict__ pred_points,   // [NI][2]
    const float* __restrict__ tgt_labels,    // [NJ][2]
    const float* __restrict__ tgt_points,    // [NJ][2]
    f32x4* __restrict__ wqa,                 // [NI]
    float* __restrict__ wpy,                 // [NI]
    f32x4* __restrict__ wtgt)                // [NJ]
{
    int tid = blockIdx.x * blockDim.x + threadIdx.x;
    if (tid < NI) {
        float x0 = pred_logits[tid * 2 + 0];
        float x1 = pred_logits[tid * 2 + 1];
        // stable softplus(x) = max(x,0) + log1p(exp(-|x|))
        float sp0 = fmaxf(x0, 0.0f) + log1pf(expf(-fabsf(x0)));
        float sp1 = fmaxf(x1, 0.0f) + log1pf(expf(-fabsf(x1)));
        f32x4 q;
        q.x = sp0 + sp1;                 // base
        q.y = -x0;                       // coeff for t0
        q.z = -x1;                       // coeff for t1
        q.w = pred_points[tid * 2 + 0];  // px
        wqa[tid] = q;
        wpy[tid] = pred_points[tid * 2 + 1];  // py
    } else if (tid < NI + NJ) {
        int j = tid - NI;
        f32x4 t;
        t.x = tgt_labels[j * 2 + 0];
        t.y = tgt_labels[j * 2 + 1];
        t.z = tgt_points[j * 2 + 0];
        t.w = tgt_points[j * 2 + 1];
        wtgt[j] = t;
    }
}

__device__ __forceinline__ float cost_elem(f32x4 q, float pyr, f32x4 t) {
    float cc = q.x + q.y * t.x + q.z * t.y;
    float cp = fabsf(q.w - t.z) + fabsf(pyr - t.w);
    return fmaf(5.0f, cp, cc);
}

// ---- main: 1D grid-stride linear writer, fill-shaped store stream.
// idx -> (i = idx/1200, jf = idx%1200) via compiler magic-division.
// 2048 blocks x 256 thr = 8192 waves = 32 waves/CU (max occupancy).
__global__ __launch_bounds__(256) void cmat_kernel(
    const f32x4* __restrict__ wqa,
    const float* __restrict__ wpy,
    const f32x4* __restrict__ wtgt,
    f32x4* __restrict__ out)                 // [NTOT] linear
{
    unsigned stride = gridDim.x * blockDim.x;
    for (unsigned idx = blockIdx.x * blockDim.x + threadIdx.x; idx < NTOT;
         idx += stride) {
        unsigned i  = idx / (unsigned)NJF;       // magic-mul, no HW divide
        unsigned jf = idx - i * (unsigned)NJF;

        f32x4 q   = wqa[i];                      // L1-hot (one line per ~19 waves)
        float pyr = wpy[i];
        f32x4 t0  = wtgt[jf * 4 + 0];            // 64B contiguous, L1/L2-hot
        f32x4 t1  = wtgt[jf * 4 + 1];
        f32x4 t2  = wtgt[jf * 4 + 2];
        f32x4 t3  = wtgt[jf * 4 + 3];

        f32x4 o;
        o.x = cost_elem(q, pyr, t0);
        o.y = cost_elem(q, pyr, t1);
        o.z = cost_elem(q, pyr, t2);
        o.w = cost_elem(q, pyr, t3);
        out[idx] = o;                            // linear coalesced 16B/lane
    }
}

extern "C" void kernel_launch(void* const* d_in, const int* in_sizes, int n_in,
                              void* d_out, int out_size, void* d_ws, size_t ws_size,
                              hipStream_t stream) {
    const float* pred_logits = (const float*)d_in[0];  // 24000
    const float* pred_points = (const float*)d_in[1];  // 24000
    const float* tgt_labels  = (const float*)d_in[2];  // 9600
    const float* tgt_points  = (const float*)d_in[3];  // 9600
    float* out = (float*)d_out;                        // 57,600,000

    // ws layout: wqa [NI] f32x4 | wpy [NI] float | wtgt [NJ] f32x4
    char* ws = (char*)d_ws;
    f32x4* wqa  = (f32x4*)ws;                          // 192,000 B
    float* wpy  = (float*)(ws + NI * sizeof(f32x4));   //  48,000 B
    f32x4* wtgt = (f32x4*)(ws + NI * sizeof(f32x4) + NI * sizeof(float));
    // total ws use: 316,800 B

    dim3 block(256);
    dim3 grid_pre((NI + NJ + 255) / 256);
    precompute_kernel<<<grid_pre, block, 0, stream>>>(
        pred_logits, pred_points, tgt_labels, tgt_points, wqa, wpy, wtgt);

    cmat_kernel<<<dim3(2048), block, 0, stream>>>(wqa, wpy, wtgt, (f32x4*)out);
}